// Round 10
// baseline (187.460 us; speedup 1.0000x reference)
//
#include <hip/hip_runtime.h>
#include <hip/hip_cooperative_groups.h>
#include <math.h>

namespace cg = cooperative_groups;

#define NB 4
#define NS 8192
#define ND 2048
#define NK 4096            // int(0.5 * NS)
#define NTOK (NB * NS)     // 32768

#define GRID 1024
#define TPB  256
#define EPT  (NS / TPB)    // 32 elems/thread in phase 2

typedef float f32x4 __attribute__((ext_vector_type(4)));

// Fused cooperative kernel:
//  phase 1: grid-stride block-per-token matvec+sigmoid (R6 inner shape)
//  grid.sync()
//  phase 2: blocks 0..3 do per-row 4-pass histogram radix top-k + mask + aux
__global__ void __launch_bounds__(TPB)
mod_router_fused(const float* __restrict__ hidden,
                 const float* __restrict__ w,
                 const float* __restrict__ bias,
                 float* __restrict__ probs,
                 float* __restrict__ mask,
                 float* __restrict__ aux)
{
    const int t   = threadIdx.x;
    const int wid = t >> 6, lane = t & 63;

    __shared__ float    lds4[2][4];
    __shared__ int      hist[256];
    __shared__ float    flds[4];
    __shared__ unsigned sbc[2];

    // ---------------- phase 1: matvec + sigmoid ----------------
    {
        const int idx0 = t * 4;
        const int idx1 = 1024 + t * 4;
        const f32x4 w0 = *reinterpret_cast<const f32x4*>(w + idx0);
        const f32x4 w1 = *reinterpret_cast<const f32x4*>(w + idx1);
        const float b0 = bias[0];

        int slot = 0;
        for (int tok = blockIdx.x; tok < NTOK; tok += GRID, slot ^= 1) {
            const float* hp = hidden + (size_t)tok * ND;
            const f32x4 h0 = *reinterpret_cast<const f32x4*>(hp + idx0);
            const f32x4 h1 = *reinterpret_cast<const f32x4*>(hp + idx1);

            float acc = h0.x * w0.x + h0.y * w0.y + h0.z * w0.z + h0.w * w0.w
                      + h1.x * w1.x + h1.y * w1.y + h1.z * w1.z + h1.w * w1.w;

#pragma unroll
            for (int off = 32; off; off >>= 1) acc += __shfl_down(acc, off, 64);

            if (lane == 0) lds4[slot][wid] = acc;
            __syncthreads();
            if (t == 0) {
                const float logit = lds4[slot][0] + lds4[slot][1]
                                  + lds4[slot][2] + lds4[slot][3] + b0;
                probs[tok] = 1.0f / (1.0f + expf(-logit));
            }
            // next iter uses the other slot; t0's reads race with nothing
        }
    }

    cg::this_grid().sync();

    // ---------------- phase 2: top-k mask + aux (blocks 0..NB-1) ----------
    const int b = blockIdx.x;
    if (b >= NB) return;

    const float* row  = probs + b * NS;
    float*       mrow = mask  + b * NS;
    const int    base = t * EPT;

    unsigned u[EPT];
    float s = 0.0f;
#pragma unroll
    for (int i = 0; i < EPT; ++i) {
        const float v = row[base + i];
        s += v;
        u[i] = __float_as_uint(v);    // sigmoid > 0 => uint order == float order
    }

    // row sum (4-wave block reduce)
#pragma unroll
    for (int off = 32; off; off >>= 1) s += __shfl_down(s, off, 64);
    if (lane == 0) flds[wid] = s;
    __syncthreads();
    const float rowsum = flds[0] + flds[1] + flds[2] + flds[3];

    // ---- 4-pass MSB radix select for the NK-th largest bit pattern ----
    unsigned prefix = 0;
    int remaining = NK;
#pragma unroll 1
    for (int pass = 0; pass < 4; ++pass) {
        const int shift = 24 - 8 * pass;
        hist[t] = 0;                      // TPB == 256
        __syncthreads();

        const unsigned pmask = (pass == 0) ? 0u : (0xFFFFFFFFu << (shift + 8));
#pragma unroll
        for (int i = 0; i < EPT; ++i)
            if ((u[i] & pmask) == prefix)
                atomicAdd(&hist[(u[i] >> shift) & 0xFF], 1);
        __syncthreads();

        if (wid == 0) {
            int cnt[4];
#pragma unroll
            for (int j = 0; j < 4; ++j) cnt[j] = hist[lane * 4 + j];
            const int mysum = cnt[0] + cnt[1] + cnt[2] + cnt[3];

            int inc = mysum;              // reverse inclusive scan (lanes >= lane)
#pragma unroll
            for (int off = 1; off < 64; off <<= 1) {
                const int y = __shfl_down(inc, off, 64);
                if (lane + off < 64) inc += y;
            }
            const int tailT = inc - mysum;

            int best = -1, subT = 0, Tj = tailT;
#pragma unroll
            for (int j = 3; j >= 0; --j) {
                const int Tnew = Tj + cnt[j];
                if (best < 0 && Tnew >= remaining) { best = lane * 4 + j; subT = Tj; }
                Tj = Tnew;
            }

#pragma unroll
            for (int off = 32; off; off >>= 1) {
                const int ob = __shfl_down(best, off, 64);
                const int os = __shfl_down(subT, off, 64);
                if (ob > best) { best = ob; subT = os; }
            }
            if (lane == 0) {
                sbc[0] = prefix | ((unsigned)best << shift);
                sbc[1] = (unsigned)(remaining - subT);
            }
        }
        __syncthreads();
        prefix    = sbc[0];
        remaining = (int)sbc[1];
    }
    const unsigned thr = prefix;
    const int need_ties = remaining;

    // ---- exclusive scan of "== thr" counts in global index order ----
    int eqc = 0;
#pragma unroll
    for (int i = 0; i < EPT; ++i) eqc += (u[i] == thr) ? 1 : 0;

    int inc = eqc;
#pragma unroll
    for (int off = 1; off < 64; off <<= 1) {
        const int y = __shfl_up(inc, off, 64);
        if (lane >= off) inc += y;
    }
    __syncthreads();                 // hist reuse barrier
    if (lane == 63) hist[wid] = inc;
    __syncthreads();
    if (t == 0) {
        int run0 = 0;
#pragma unroll
        for (int wv = 0; wv < 4; ++wv) { const int x = hist[wv]; hist[wv] = run0; run0 += x; }
    }
    __syncthreads();
    int run = (inc - eqc) + hist[wid];

    // ---- write mask ----
#pragma unroll
    for (int i = 0; i < EPT; ++i) {
        float m;
        if (u[i] > thr)       m = 1.0f;
        else if (u[i] == thr) { m = (run < need_ties) ? 1.0f : 0.0f; ++run; }
        else                  m = 0.0f;
        mrow[base + i] = m;
    }

    // ---- aux loss ----
    if (t == 0) {
        const float mean = rowsum * (1.0f / (float)NS);
        const float d = mean - 0.5f;
        aux[b] = 0.01f * d * d;
    }
}

extern "C" void kernel_launch(void* const* d_in, const int* in_sizes, int n_in,
                              void* d_out, int out_size, void* d_ws, size_t ws_size,
                              hipStream_t stream)
{
    const float* hidden = (const float*)d_in[0];   // [NB, NS, ND] f32
    const float* w      = (const float*)d_in[1];   // [ND] f32
    const float* bias   = (const float*)d_in[2];   // scalar f32

    float* out   = (float*)d_out;
    float* probs = out;                 // [NB, NS]
    float* mask  = out + NB * NS;       // [NB, NS]
    float* aux   = out + 2 * NB * NS;   // [NB]

    void* args[] = { (void*)&hidden, (void*)&w, (void*)&bias,
                     (void*)&probs, (void*)&mask, (void*)&aux };
    hipLaunchCooperativeKernel(reinterpret_cast<void*>(mod_router_fused),
                               dim3(GRID), dim3(TPB), args, 0, stream);
}

// Round 11
// 55.139 us; speedup vs baseline: 3.3998x; 3.3998x over previous
//
#include <hip/hip_runtime.h>
#include <math.h>

#define NB 4
#define NS 8192
#define ND 2048
#define NK 4096   // int(0.5 * NS)

#define TPB 512                        // 2 tokens per block, 256 thr each
#define MV_BLOCKS ((NB * NS) / 2)      // 16384

typedef float f32x4 __attribute__((ext_vector_type(4)));

// ------- Kernel 1: matvec + sigmoid (2 tokens per 512-thread block) --------
// Each 256-thread half owns one token with the proven R6 access pattern
// (thread tt loads float4s at tt*4 and 1024+tt*4). Halves are independent;
// one shared barrier serves both. Halves the dispatch count and w reloads
// vs R6 while keeping full occupancy (4 blocks x 512 thr = 2048 thr/CU).
__global__ void __launch_bounds__(TPB)
router_matvec(const float* __restrict__ hidden,
              const float* __restrict__ w,
              const float* __restrict__ bias,
              float* __restrict__ probs)
{
    const int t    = threadIdx.x;
    const int half = t >> 8;               // 0 or 1
    const int tt   = t & 255;
    const int wid  = t >> 6;               // 0..7 (block-wide wave id)
    const int lane = t & 63;

    const int token = blockIdx.x * 2 + half;
    const float* hp = hidden + (size_t)token * ND;

    const int idx0 = tt * 4;
    const int idx1 = 1024 + tt * 4;

    const f32x4 w0 = *reinterpret_cast<const f32x4*>(w + idx0);
    const f32x4 w1 = *reinterpret_cast<const f32x4*>(w + idx1);
    const f32x4 h0 = *reinterpret_cast<const f32x4*>(hp + idx0);
    const f32x4 h1 = *reinterpret_cast<const f32x4*>(hp + idx1);

    float acc = h0.x * w0.x + h0.y * w0.y + h0.z * w0.z + h0.w * w0.w
              + h1.x * w1.x + h1.y * w1.y + h1.z * w1.z + h1.w * w1.w;

#pragma unroll
    for (int off = 32; off; off >>= 1) acc += __shfl_down(acc, off, 64);

    __shared__ float lds[8];
    if (lane == 0) lds[wid] = acc;
    __syncthreads();
    if (tt == 0) {                          // t==0 and t==256
        const int base4 = half * 4;
        const float logit = lds[base4 + 0] + lds[base4 + 1]
                          + lds[base4 + 2] + lds[base4 + 3] + bias[0];
        probs[token] = 1.0f / (1.0f + expf(-logit));
    }
}

// ---------------- Kernel 2: per-row top-k mask + aux loss (R4 version) -----
// 1024 threads per batch row; 4-pass 8-bit histogram radix select.

__device__ __forceinline__ float block_reduce_float(float v, float* lds)
{
#pragma unroll
    for (int off = 32; off; off >>= 1) v += __shfl_down(v, off, 64);
    const int wid = threadIdx.x >> 6, lane = threadIdx.x & 63;
    __syncthreads();
    if (lane == 0) lds[wid] = v;
    __syncthreads();
    float s = 0.0f;
#pragma unroll
    for (int i = 0; i < 16; ++i) s += lds[i];
    return s;
}

__global__ void __launch_bounds__(1024)
topk_mask(const float* __restrict__ probs,
          float* __restrict__ mask,
          float* __restrict__ aux)
{
    const int b = blockIdx.x;
    const float* row = probs + b * NS;
    float*      mrow = mask  + b * NS;

    const int t = threadIdx.x;
    const int base = t * 8;
    const int wid = t >> 6, lane = t & 63;

    __shared__ int      hist[256];
    __shared__ float    flds[16];
    __shared__ unsigned sbc[2];     // [0]=prefix, [1]=remaining

    float    v[8];
    unsigned u[8];
#pragma unroll
    for (int i = 0; i < 8; ++i) {
        v[i] = row[base + i];
        u[i] = __float_as_uint(v[i]);   // sigmoid > 0 => uint order == float order
    }

    // ---- row sum (deterministic) for aux loss ----
    float s = 0.0f;
#pragma unroll
    for (int i = 0; i < 8; ++i) s += v[i];
    const float rowsum = block_reduce_float(s, flds);

    // ---- 4-pass MSB radix select for the NK-th largest bit pattern ----
    unsigned prefix = 0;      // resolved high bits
    int remaining = NK;       // rank still needed inside the prefix group
#pragma unroll 1
    for (int pass = 0; pass < 4; ++pass) {
        const int shift = 24 - 8 * pass;
        if (t < 256) hist[t] = 0;
        __syncthreads();

        const unsigned pmask = (pass == 0) ? 0u : (0xFFFFFFFFu << (shift + 8));
#pragma unroll
        for (int i = 0; i < 8; ++i)
            if ((u[i] & pmask) == prefix)
                atomicAdd(&hist[(u[i] >> shift) & 0xFF], 1);
        __syncthreads();

        if (wid == 0) {
            // lane owns bins 4*lane .. 4*lane+3
            int cnt[4];
#pragma unroll
            for (int j = 0; j < 4; ++j) cnt[j] = hist[lane * 4 + j];
            const int mysum = cnt[0] + cnt[1] + cnt[2] + cnt[3];

            // reverse inclusive scan: inc = sum over lanes >= lane
            int inc = mysum;
#pragma unroll
            for (int off = 1; off < 64; off <<= 1) {
                const int y = __shfl_down(inc, off, 64);
                if (lane + off < 64) inc += y;
            }
            const int tailT = inc - mysum;   // count strictly above this lane's bins

            // local candidate: max bin d (scan j descending) with T[d] >= remaining
            int best = -1, subT = 0, Tj = tailT;
#pragma unroll
            for (int j = 3; j >= 0; --j) {
                const int Tnew = Tj + cnt[j];          // T[4*lane+j]
                if (best < 0 && Tnew >= (int)remaining) { best = lane * 4 + j; subT = Tj; }
                Tj = Tnew;
            }

            // wave max-reduce on best, carrying subT (= count strictly above best)
#pragma unroll
            for (int off = 32; off; off >>= 1) {
                const int ob = __shfl_down(best, off, 64);
                const int os = __shfl_down(subT, off, 64);
                if (ob > best) { best = ob; subT = os; }
            }
            if (lane == 0) {
                sbc[0] = prefix | ((unsigned)best << shift);
                sbc[1] = (unsigned)(remaining - subT);
            }
        }
        __syncthreads();
        prefix    = sbc[0];
        remaining = (int)sbc[1];
    }
    const unsigned thr = prefix;     // exact bits of the NK-th largest value
    const int need_ties = remaining; // # elements equal to thr to take (lowest idx first)

    // ---- exclusive scan of per-element "== thr" counts in global index order ----
    int eqc = 0;
#pragma unroll
    for (int i = 0; i < 8; ++i) eqc += (u[i] == thr) ? 1 : 0;

    int inc = eqc;                   // wave-level inclusive scan
#pragma unroll
    for (int off = 1; off < 64; off <<= 1) {
        const int y = __shfl_up(inc, off, 64);
        if (lane >= off) inc += y;
    }
    __syncthreads();
    if (lane == 63) hist[wid] = inc;
    __syncthreads();
    if (t == 0) {
        int run = 0;
#pragma unroll
        for (int wv = 0; wv < 16; ++wv) { const int x = hist[wv]; hist[wv] = run; run += x; }
    }
    __syncthreads();
    int run = (inc - eqc) + hist[wid];

    // ---- write mask ----
#pragma unroll
    for (int i = 0; i < 8; ++i) {
        float m;
        if (u[i] > thr)       m = 1.0f;
        else if (u[i] == thr) { m = (run < need_ties) ? 1.0f : 0.0f; ++run; }
        else                  m = 0.0f;
        mrow[base + i] = m;
    }

    // ---- aux loss ----
    if (t == 0) {
        const float mean = rowsum * (1.0f / (float)NS);
        const float d = mean - 0.5f;
        aux[b] = 0.01f * d * d;
    }
}

extern "C" void kernel_launch(void* const* d_in, const int* in_sizes, int n_in,
                              void* d_out, int out_size, void* d_ws, size_t ws_size,
                              hipStream_t stream)
{
    const float* hidden = (const float*)d_in[0];   // [NB, NS, ND] f32
    const float* w      = (const float*)d_in[1];   // [ND] f32
    const float* bias   = (const float*)d_in[2];   // scalar f32

    float* out   = (float*)d_out;
    float* probs = out;                 // [NB, NS]
    float* mask  = out + NB * NS;       // [NB, NS]
    float* aux   = out + 2 * NB * NS;   // [NB]

    router_matvec<<<MV_BLOCKS, TPB, 0, stream>>>(hidden, w, bias, probs);
    topk_mask<<<NB, 1024, 0, stream>>>(probs, mask, aux);
}